// Round 6
// baseline (404.635 us; speedup 1.0000x reference)
//
#include <hip/hip_runtime.h>

#define BB 128
#define SS 512
#define HH 1024
#define NB 16   // sum blocks per batch; grid (NB, BB) = 2048 blocks, all resident

typedef float f32x4 __attribute__((ext_vector_type(4)));

// ---------------------------------------------------------------------------
// Per-block meta: int4 {t_begin, t_end, l_begin, l_end} for batch b.
// 256 threads. Exactly-3-SEP data makes the thread-0 scan ~10 instructions.
// ---------------------------------------------------------------------------
__device__ __forceinline__ int4 compute_meta(const int* __restrict__ ids,
                                             const int* __restrict__ attn,
                                             int b, int sep) {
    __shared__ unsigned long long words[SS / 64];
    __shared__ int sh_p[4];      // p1, p2, p3, cnt
    __shared__ int sh_mask;
    const int t = threadIdx.x;   // 0..255
    const int* row = ids + b * SS;
    const int tok0 = row[t];
    const int tok1 = row[t + 256];
    const unsigned long long b0 = __ballot(tok0 == sep);
    const unsigned long long b1 = __ballot(tok1 == sep);
    if ((t & 63) == 0) {
        words[t >> 6] = b0;
        words[4 + (t >> 6)] = b1;
    }
    if (t == 0) sh_mask = 0;
    __syncthreads();
    if (t == 0) {
        int cnt = 0, p1 = 0, p2 = 0, p3 = 0;
        for (int i = 0; i < SS / 64; ++i) {
            unsigned long long word = words[i];
            while (word && cnt < 3) {
                const int pos = i * 64 + __builtin_ctzll(word);
                ++cnt;
                if (cnt == 1) p1 = pos;
                else if (cnt == 2) p2 = pos;
                else p3 = pos;
                word &= word - 1;
            }
        }
        sh_p[0] = p1; sh_p[1] = p2; sh_p[2] = p3; sh_p[3] = cnt;
    }
    __syncthreads();
    const int cnt = sh_p[3];
    if (cnt < 3) {   // block-uniform rare branch: mask_len fallback
        const int* arow = attn + b * SS;
        atomicAdd(&sh_mask, arow[t] + arow[t + 256]);
        __syncthreads();
    }
    int4 m;
    if (cnt >= 2) {
        m.x = 1;
        m.y = max(sh_p[0], 1);           // title [1, p1)
        m.z = sh_p[1] + 1;               // lead begin
        const int e = (cnt >= 3) ? sh_p[2] : sh_mask;
        m.w = max(e, m.z);               // lead end (clamped)
    } else {
        m.x = 0; m.y = 0; m.z = 0; m.w = 0;
    }
    return m;
}

// ---------------------------------------------------------------------------
// Fused kernel: balanced contiguous partial sums + last-block-per-batch
// finalize. grid = (NB, BB), 256 threads.
// Block nb of batch b owns union range [nb*T/NB, (nb+1)*T/NB) where
// u < t_len -> title row m.x+u, else lead row m.z+(u-t_len).
// Partials slot validity is a closed-form predicate both the writer and the
// gathering last block compute identically -> poisoned ws never read.
// counters[b] must be 0 at launch (memset below); last block resets it to 0
// so the buffer state is identical across graph replays.
// ---------------------------------------------------------------------------
__global__ void __launch_bounds__(256)
seg_fused(const float* __restrict__ hs,
          const int* __restrict__ ids,
          const int* __restrict__ attn,
          const int* __restrict__ sep_tok,
          float* __restrict__ partials,
          unsigned* __restrict__ counters,
          float* __restrict__ out) {
    const int nb = blockIdx.x;
    const int b  = blockIdx.y;
    const int4 m = compute_meta(ids, attn, b, sep_tok[0]);
    const int t_len = m.y - m.x;
    const int l_len = m.w - m.z;
    const int T = t_len + l_len;

    const int u0 = (nb * T) / NB;
    const int u1 = ((nb + 1) * T) / NB;

    const int h4 = threadIdx.x;
    const f32x4* base = (const f32x4*)(hs + (size_t)b * SS * HH);
    f32x4* p = (f32x4*)(partials + (size_t)(b * NB + nb) * 2 * HH);

    // title part of this block's union range
    const int tA = u0, tB = min(u1, t_len);
    if (tA < tB) {
        f32x4 a = {0.f, 0.f, 0.f, 0.f};
        #pragma unroll 4
        for (int u = tA; u < tB; ++u)
            a += base[(size_t)(m.x + u) * (HH / 4) + h4];
        p[h4] = a;
    }
    // lead part of this block's union range
    const int lA = max(u0, t_len), lB = u1;
    if (lA < lB) {
        f32x4 a = {0.f, 0.f, 0.f, 0.f};
        #pragma unroll 4
        for (int u = lA; u < lB; ++u)
            a += base[(size_t)(m.z + (u - t_len)) * (HH / 4) + h4];
        p[HH / 4 + h4] = a;
    }

    // ---- completion protocol (threadFenceReduction pattern) ----
    __threadfence();                 // publish this block's partials (device scope)
    __syncthreads();                 // all threads' stores issued before announce
    __shared__ int sh_last;
    if (threadIdx.x == 0) {
        const unsigned old = atomicAdd(&counters[b], 1u);
        sh_last = (old == NB - 1) ? 1 : 0;
        if (sh_last) atomicExch(&counters[b], 0u);  // restore state for next call
    }
    __syncthreads();
    if (!sh_last) return;
    __threadfence();                 // acquire: no stale partials

    // ---- finalize batch b: gather valid slots, divide / CLS fallback ----
    f32x4 at = {0.f, 0.f, 0.f, 0.f};
    f32x4 al = {0.f, 0.f, 0.f, 0.f};
    #pragma unroll
    for (int k = 0; k < NB; ++k) {
        const int v0 = (k * T) / NB;
        const int v1 = ((k + 1) * T) / NB;
        const f32x4* pk = (const f32x4*)(partials + (size_t)(b * NB + k) * 2 * HH);
        if (v0 < min(v1, t_len)) at += pk[h4];
        if (max(v0, t_len) < v1) al += pk[HH / 4 + h4];
    }

    f32x4 cls = {0.f, 0.f, 0.f, 0.f};
    if (t_len <= 0 || l_len <= 0)
        cls = ((const f32x4*)(hs + (size_t)b * SS * HH))[h4];  // CLS row

    const f32x4 o0 = (t_len > 0) ? at / (float)t_len : cls;
    const f32x4 o1 = (l_len > 0) ? al / (float)l_len : cls;

    ((f32x4*)out)[(size_t)b * (HH / 4) + h4] = o0;
    ((f32x4*)out)[(size_t)(BB + b) * (HH / 4) + h4] = o1;
}

// ---------------------------------------------------------------------------
extern "C" void kernel_launch(void* const* d_in, const int* in_sizes, int n_in,
                              void* d_out, int out_size, void* d_ws, size_t ws_size,
                              hipStream_t stream) {
    const float* hs  = (const float*)d_in[0];
    const int*   ids = (const int*)d_in[1];
    const int*   am  = (const int*)d_in[2];
    const int*   sep = (const int*)d_in[3];
    float* out = (float*)d_out;

    unsigned* counters = (unsigned*)d_ws;                   // 128 * 4 B
    float* partials = (float*)((char*)d_ws + 1024);         // 16 MB

    // counters must start at 0 (ws is poisoned to 0xAA before timing);
    // the kernel's last block per batch resets its counter to 0, so state is
    // identical on every call.
    hipMemsetAsync(counters, 0, BB * sizeof(unsigned), stream);
    seg_fused<<<dim3(NB, BB), 256, 0, stream>>>(hs, ids, am, sep,
                                                partials, counters, out);
}

// Round 7
// 63.222 us; speedup vs baseline: 6.4002x; 6.4002x over previous
//
#include <hip/hip_runtime.h>

#define BB 128
#define SS 512
#define HH 1024
#define NB 16   // sum blocks per batch; grid (NB, BB) = 2048 blocks

typedef float f32x4 __attribute__((ext_vector_type(4)));

// ---------------------------------------------------------------------------
// Per-block meta: int4 {t_begin, t_end, l_begin, l_end} for batch b.
// 256 threads. Exactly-3-SEP data makes the thread-0 scan ~10 instructions.
// ---------------------------------------------------------------------------
__device__ __forceinline__ int4 compute_meta(const int* __restrict__ ids,
                                             const int* __restrict__ attn,
                                             int b, int sep) {
    __shared__ unsigned long long words[SS / 64];
    __shared__ int sh_p[4];      // p1, p2, p3, cnt
    __shared__ int sh_mask;
    const int t = threadIdx.x;   // 0..255
    const int* row = ids + b * SS;
    const int tok0 = row[t];
    const int tok1 = row[t + 256];
    const unsigned long long b0 = __ballot(tok0 == sep);
    const unsigned long long b1 = __ballot(tok1 == sep);
    if ((t & 63) == 0) {
        words[t >> 6] = b0;
        words[4 + (t >> 6)] = b1;
    }
    if (t == 0) sh_mask = 0;
    __syncthreads();
    if (t == 0) {
        int cnt = 0, p1 = 0, p2 = 0, p3 = 0;
        for (int i = 0; i < SS / 64; ++i) {
            unsigned long long word = words[i];
            while (word && cnt < 3) {
                const int pos = i * 64 + __builtin_ctzll(word);
                ++cnt;
                if (cnt == 1) p1 = pos;
                else if (cnt == 2) p2 = pos;
                else p3 = pos;
                word &= word - 1;
            }
        }
        sh_p[0] = p1; sh_p[1] = p2; sh_p[2] = p3; sh_p[3] = cnt;
    }
    __syncthreads();
    const int cnt = sh_p[3];
    if (cnt < 3) {   // block-uniform rare branch: mask_len fallback
        const int* arow = attn + b * SS;
        atomicAdd(&sh_mask, arow[t] + arow[t + 256]);
        __syncthreads();
    }
    int4 m;
    if (cnt >= 2) {
        m.x = 1;
        m.y = max(sh_p[0], 1);           // title [1, p1)
        m.z = sh_p[1] + 1;               // lead begin
        const int e = (cnt >= 3) ? sh_p[2] : sh_mask;
        m.w = max(e, m.z);               // lead end (clamped)
    } else {
        m.x = 0; m.y = 0; m.z = 0; m.w = 0;
    }
    return m;
}

// ---------------------------------------------------------------------------
// Fused kernel, atomic-only coherence (NO __threadfence -> no L2 writeback).
// grid = (NB, BB), 256 threads. Block nb of batch b owns contiguous union
// range [nb*T/NB, (nb+1)*T/NB); u < t_len -> title row m.x+u, else lead row
// m.z + (u - t_len). Partial sums go straight into sums[b][2][HH] via HW f32
// atomics (coherence-point RMW, no dirty L2). Completion: counters[b] bump
// AFTER __syncthreads' vmcnt(0) drain; block seeing old==NB-1 re-reads sums
// with agent-scope atomic loads (coherent, no cache maintenance) and writes
// the two outputs.
// ---------------------------------------------------------------------------
__global__ void __launch_bounds__(256)
seg_fused_atomic(const float* __restrict__ hs,
                 const int* __restrict__ ids,
                 const int* __restrict__ attn,
                 const int* __restrict__ sep_tok,
                 unsigned* __restrict__ counters,
                 float* __restrict__ sums,
                 float* __restrict__ out) {
    const int nb = blockIdx.x;
    const int b  = blockIdx.y;
    const int4 m = compute_meta(ids, attn, b, sep_tok[0]);
    const int t_len = m.y - m.x;
    const int l_len = m.w - m.z;
    const int T = t_len + l_len;

    const int u0 = (nb * T) / NB;
    const int u1 = ((nb + 1) * T) / NB;

    const int h4 = threadIdx.x;
    const f32x4* base = (const f32x4*)(hs + (size_t)b * SS * HH);
    float* st = sums + ((size_t)b * 2 + 0) * HH + h4 * 4;
    float* sl = sums + ((size_t)b * 2 + 1) * HH + h4 * 4;

    // title part of this block's union range
    const int tA = u0, tB = min(u1, t_len);
    if (tA < tB) {
        f32x4 a = {0.f, 0.f, 0.f, 0.f};
        #pragma unroll 4
        for (int u = tA; u < tB; ++u)
            a += base[(size_t)(m.x + u) * (HH / 4) + h4];
        unsafeAtomicAdd(st + 0, a.x); unsafeAtomicAdd(st + 1, a.y);
        unsafeAtomicAdd(st + 2, a.z); unsafeAtomicAdd(st + 3, a.w);
    }
    // lead part of this block's union range
    const int lA = max(u0, t_len), lB = u1;
    if (lA < lB) {
        f32x4 a = {0.f, 0.f, 0.f, 0.f};
        #pragma unroll 4
        for (int u = lA; u < lB; ++u)
            a += base[(size_t)(m.z + (u - t_len)) * (HH / 4) + h4];
        unsafeAtomicAdd(sl + 0, a.x); unsafeAtomicAdd(sl + 1, a.y);
        unsafeAtomicAdd(sl + 2, a.z); unsafeAtomicAdd(sl + 3, a.w);
    }

    // ---- completion protocol: atomics only, no cache-maintenance fences ----
    asm volatile("s_waitcnt vmcnt(0)" ::: "memory");  // my atomics are ACKed
    __syncthreads();                                  // whole block done (also drains)
    __shared__ unsigned sh_old;
    if (threadIdx.x == 0)
        sh_old = __hip_atomic_fetch_add(&counters[b], 1u,
                                        __ATOMIC_RELAXED, __HIP_MEMORY_SCOPE_AGENT);
    __syncthreads();
    if (sh_old != NB - 1) return;

    // ---- last block of batch b: coherent re-read, divide / CLS fallback ----
    f32x4 at, al;
    #pragma unroll
    for (int j = 0; j < 4; ++j)
        at[j] = __hip_atomic_load(st + j, __ATOMIC_RELAXED, __HIP_MEMORY_SCOPE_AGENT);
    #pragma unroll
    for (int j = 0; j < 4; ++j)
        al[j] = __hip_atomic_load(sl + j, __ATOMIC_RELAXED, __HIP_MEMORY_SCOPE_AGENT);

    f32x4 cls = {0.f, 0.f, 0.f, 0.f};
    if (t_len <= 0 || l_len <= 0)
        cls = ((const f32x4*)(hs + (size_t)b * SS * HH))[h4];  // CLS row

    const f32x4 o0 = (t_len > 0) ? at / (float)t_len : cls;
    const f32x4 o1 = (l_len > 0) ? al / (float)l_len : cls;

    ((f32x4*)out)[(size_t)b * (HH / 4) + h4] = o0;
    ((f32x4*)out)[(size_t)(BB + b) * (HH / 4) + h4] = o1;
}

// ---------------------------------------------------------------------------
extern "C" void kernel_launch(void* const* d_in, const int* in_sizes, int n_in,
                              void* d_out, int out_size, void* d_ws, size_t ws_size,
                              hipStream_t stream) {
    const float* hs  = (const float*)d_in[0];
    const int*   ids = (const int*)d_in[1];
    const int*   am  = (const int*)d_in[2];
    const int*   sep = (const int*)d_in[3];
    float* out = (float*)d_out;

    unsigned* counters = (unsigned*)d_ws;                 // [0, 512)
    float* sums = (float*)((char*)d_ws + 1024);           // 1 MB: sums[BB][2][HH]

    // Zero counters + sums every call (in the captured graph -> every replay).
    hipMemsetAsync(d_ws, 0, 1024 + (size_t)BB * 2 * HH * sizeof(float), stream);
    seg_fused_atomic<<<dim3(NB, BB), 256, 0, stream>>>(hs, ids, am, sep,
                                                       counters, sums, out);
}

// Round 8
// 44.603 us; speedup vs baseline: 9.0719x; 1.4174x over previous
//
#include <hip/hip_runtime.h>

#define BB 128
#define SS 512
#define HH 1024
#define NB 16   // sum-pass blocks per batch

typedef float f32x4 __attribute__((ext_vector_type(4)));

// d_ws layout:
//   [0, 2048)        : int4 meta[BB]   (written by kernel1's nb==0 blocks)
//   [4096, 4096+16MB): float partials[BB][NB][2][HH]

// ---------------------------------------------------------------------------
// Per-block meta: int4 {t_begin, t_end, l_begin, l_end} for batch b.
// 256 threads. Exactly-3-SEP data makes the thread-0 scan ~10 instructions.
// ---------------------------------------------------------------------------
__device__ __forceinline__ int4 compute_meta(const int* __restrict__ ids,
                                             const int* __restrict__ attn,
                                             int b, int sep) {
    __shared__ unsigned long long words[SS / 64];
    __shared__ int sh_p[4];      // p1, p2, p3, cnt
    __shared__ int sh_mask;
    const int t = threadIdx.x;   // 0..255
    const int* row = ids + b * SS;
    const int tok0 = row[t];
    const int tok1 = row[t + 256];
    const unsigned long long b0 = __ballot(tok0 == sep);
    const unsigned long long b1 = __ballot(tok1 == sep);
    if ((t & 63) == 0) {
        words[t >> 6] = b0;
        words[4 + (t >> 6)] = b1;
    }
    if (t == 0) sh_mask = 0;
    __syncthreads();
    if (t == 0) {
        int cnt = 0, p1 = 0, p2 = 0, p3 = 0;
        for (int i = 0; i < SS / 64; ++i) {
            unsigned long long word = words[i];
            while (word && cnt < 3) {
                const int pos = i * 64 + __builtin_ctzll(word);
                ++cnt;
                if (cnt == 1) p1 = pos;
                else if (cnt == 2) p2 = pos;
                else p3 = pos;
                word &= word - 1;
            }
        }
        sh_p[0] = p1; sh_p[1] = p2; sh_p[2] = p3; sh_p[3] = cnt;
    }
    __syncthreads();
    const int cnt = sh_p[3];
    if (cnt < 3) {   // block-uniform rare branch: mask_len fallback
        const int* arow = attn + b * SS;
        atomicAdd(&sh_mask, arow[t] + arow[t + 256]);
        __syncthreads();
    }
    int4 m;
    if (cnt >= 2) {
        m.x = 1;
        m.y = max(sh_p[0], 1);           // title [1, p1)
        m.z = sh_p[1] + 1;               // lead begin
        const int e = (cnt >= 3) ? sh_p[2] : sh_mask;
        m.w = max(e, m.z);               // lead end (clamped)
    } else {
        m.x = 0; m.y = 0; m.z = 0; m.w = 0;
    }
    return m;
}

// ---------------------------------------------------------------------------
// Kernel 1: balanced contiguous partial sums (round-4 skeleton, proven).
// grid = (NB, BB), 256 threads. Block nb of batch b owns union range
// [nb*T/NB, (nb+1)*T/NB); u < t_len -> title row m.x+u, else lead row
// m.z + (u - t_len). Writes partials[b][nb][2][HH] only for touched halves;
// finalize derives identical touch-predicates from meta[b], so poisoned ws
// is never read. nb==0 block also publishes meta[b] for the finalize pass.
// ---------------------------------------------------------------------------
__global__ void __launch_bounds__(256)
seg_sum_balanced(const float* __restrict__ hs,
                 const int* __restrict__ ids,
                 const int* __restrict__ attn,
                 const int* __restrict__ sep_tok,
                 int4* __restrict__ meta,
                 float* __restrict__ partials) {
    const int nb = blockIdx.x;
    const int b  = blockIdx.y;
    const int4 m = compute_meta(ids, attn, b, sep_tok[0]);
    const int t_len = m.y - m.x;
    const int l_len = m.w - m.z;
    const int T = t_len + l_len;

    if (nb == 0 && threadIdx.x == 0) meta[b] = m;   // publish for finalize

    const int u0 = (nb * T) / NB;
    const int u1 = ((nb + 1) * T) / NB;

    const int h4 = threadIdx.x;
    const f32x4* base = (const f32x4*)(hs + (size_t)b * SS * HH);
    f32x4* p = (f32x4*)(partials + (size_t)(b * NB + nb) * 2 * HH);

    // title part of this block's union range
    const int tA = u0, tB = min(u1, t_len);
    if (tA < tB) {
        f32x4 a = {0.f, 0.f, 0.f, 0.f};
        #pragma unroll 4
        for (int u = tA; u < tB; ++u)
            a += base[(size_t)(m.x + u) * (HH / 4) + h4];
        p[h4] = a;
    }
    // lead part of this block's union range
    const int lA = max(u0, t_len), lB = u1;
    if (lA < lB) {
        f32x4 a = {0.f, 0.f, 0.f, 0.f};
        #pragma unroll 4
        for (int u = lA; u < lB; ++u)
            a += base[(size_t)(m.z + (u - t_len)) * (HH / 4) + h4];
        p[HH / 4 + h4] = a;
    }
}

// ---------------------------------------------------------------------------
// Kernel 2: lightweight finalize. grid = (BB), 512 threads.
// lane < 256 -> title (span 0), lane >= 256 -> lead (span 1).
// Reads meta[b] (16 B) instead of recomputing; gathers valid partial slots
// (same closed-form predicate as the writer), divides / CLS fallback.
// ---------------------------------------------------------------------------
__global__ void __launch_bounds__(512)
seg_final_lite(const float* __restrict__ hs,
               const int4* __restrict__ meta,
               const float* __restrict__ partials,
               float* __restrict__ out) {
    const int b    = blockIdx.x;
    const int span = threadIdx.x >> 8;      // 0 = title, 1 = lead
    const int h4   = threadIdx.x & 255;

    const int4 m = meta[b];
    const int t_len = m.y - m.x;
    const int l_len = m.w - m.z;
    const int T = t_len + l_len;
    const int cntr = (span == 0) ? t_len : l_len;

    f32x4 a = {0.f, 0.f, 0.f, 0.f};
    #pragma unroll
    for (int k = 0; k < NB; ++k) {
        const int v0 = (k * T) / NB;
        const int v1 = ((k + 1) * T) / NB;
        bool valid;
        if (span == 0) valid = v0 < min(v1, t_len);
        else           valid = max(v0, t_len) < v1;
        if (valid) {
            const f32x4* p = (const f32x4*)(partials +
                (size_t)(b * NB + k) * 2 * HH + (size_t)span * HH);
            a += p[h4];
        }
    }

    f32x4 o;
    if (cntr > 0) {
        o = a / (float)cntr;
    } else {
        o = ((const f32x4*)(hs + (size_t)b * SS * HH))[h4];  // CLS row
    }
    ((f32x4*)out)[(size_t)(span * BB + b) * (HH / 4) + h4] = o;
}

// ---------------------------------------------------------------------------
extern "C" void kernel_launch(void* const* d_in, const int* in_sizes, int n_in,
                              void* d_out, int out_size, void* d_ws, size_t ws_size,
                              hipStream_t stream) {
    const float* hs  = (const float*)d_in[0];
    const int*   ids = (const int*)d_in[1];
    const int*   am  = (const int*)d_in[2];
    const int*   sep = (const int*)d_in[3];
    float* out = (float*)d_out;

    int4*  meta     = (int4*)d_ws;
    float* partials = (float*)((char*)d_ws + 4096);   // 16 MB (ws is ~1 GiB)

    seg_sum_balanced<<<dim3(NB, BB), 256, 0, stream>>>(hs, ids, am, sep,
                                                       meta, partials);
    seg_final_lite<<<BB, 512, 0, stream>>>(hs, meta, partials, out);
}